// Round 14
// baseline (222.000 us; speedup 1.0000x reference)
//
#include <hip/hip_runtime.h>

#define NN 50000
#define NE 800000
#define DD 128
#define NSTRIP 3125   // NN/16
#define NB 196        // dst>>8 buckets (49999>>8 == 195)
#define CHUNK 4096    // edges per shuf block; 196 chunks
#define MAXB 6144     // bucket capacity (mean 4096, sigma ~64)

// workspace layout, element (4-byte word) offsets
#define OF_LCNT  0            // int[256*196] per-bucket-per-block counts, bucket-major
#define OF_LOFS  50176        // int[256*196] per-block local offsets, bucket-major
#define OF_DINV  100352       // float[NN]
#define OF_OFFS2 150528       // int2[NN]
#define OF_TMP2  250624       // uint[196*CHUNK] block-major slabs, bucket-grouped
#define OF_CSRU  1053440      // ushort[196*MAXB] padded sorted src
#define OF_H1    1655552      // ushort[NN*DD] bf16 h1 = x@W1 (unscaled)
#define OF_G1    4855552      // ushort[NN*DD] bf16 g1 = dinv*h1
#define OF_XH    8055552      // ushort[NN*DD] x2 bf16-hi
#define OF_XL    11255552     // ushort[NN*DD] x2 bf16-lo
#define OF_G2    14455552     // ushort[NN*DD] bf16 g2 = dinv*(x2@W2)
#define OF_W1H   17655552     // ushort[16384] fragment order
#define OF_W1L   17663744
#define OF_W2H   17671936
#define OF_W2L   17680128     // end 17688320 words = 70.8 MB

typedef __attribute__((ext_vector_type(8))) short bf8_t;   // 8 bf16 = 4 VGPRs
typedef __attribute__((ext_vector_type(8))) unsigned short us8;
typedef __attribute__((ext_vector_type(4))) float f32x4;

static __device__ __forceinline__ unsigned short f2bf(float f) {
    unsigned int u = __float_as_uint(f);
    unsigned int r = (u + 0x7fffu + ((u >> 16) & 1u)) >> 16;   // RNE
    return (unsigned short)r;
}
static __device__ __forceinline__ float bf2f(unsigned short h) {
    return __uint_as_float(((unsigned int)h) << 16);
}

// W1+W2 -> bf16 hi/lo split in B-fragment-contiguous order.
// frag g=(ntile*4+kk)*64+lane holds B[k=kk*32+(lane>>4)*8+j][n=ntile*16+(lane&15)]
__global__ void k_wconv(const float* __restrict__ W1, const float* __restrict__ W2,
                        ushort* __restrict__ w1h, ushort* __restrict__ w1l,
                        ushort* __restrict__ w2h, ushort* __restrict__ w2l) {
    int gg = blockIdx.x * 256 + threadIdx.x;
    const float* W = (gg < 2048) ? W1 : W2;
    ushort* wh = (gg < 2048) ? w1h : w2h;
    ushort* wl = (gg < 2048) ? w1l : w2l;
    int g = gg & 2047;
    int ntile = g >> 8;
    int kk = (g >> 6) & 3;
    int lane = g & 63;
    int k0 = kk * 32 + ((lane >> 4) * 8);
    int col = ntile * 16 + (lane & 15);
#pragma unroll
    for (int j = 0; j < 8; ++j) {
        float w = W[(k0 + j) * DD + col];
        unsigned short h = f2bf(w);
        wh[(size_t)g * 8 + j] = h;
        wl[(size_t)g * 8 + j] = f2bf(w - bf2f(h));
    }
}

// FUSED prep launch: blocks 0..195 = cursor-free edge shuffle;
// blocks 196..977 = layer-1 MFMA GEMM (independent work, co-scheduled).
__global__ __launch_bounds__(256) void k_prep(
        const int* __restrict__ src, const int* __restrict__ dst,
        int* __restrict__ lcnt_g, int* __restrict__ lofs_g,
        unsigned int* __restrict__ tmp2,
        const float* __restrict__ X,
        const ushort* __restrict__ wh, const ushort* __restrict__ wl,
        ushort* __restrict__ H1) {
    __shared__ int lcnt[256];
    __shared__ int lsc[256];
    __shared__ int lcur[256];
    int tid = threadIdx.x;
    if (blockIdx.x < 196) {
        int blk = blockIdx.x;
        lcnt[tid] = 0;
        __syncthreads();
        int e0 = blk * CHUNK;
        int e1 = e0 + CHUNK; if (e1 > NE) e1 = NE;
        for (int e = e0 + tid; e < e1; e += 256)
            atomicAdd(&lcnt[dst[e] >> 8], 1);
        __syncthreads();
        int v = lcnt[tid];
        lsc[tid] = v;
        __syncthreads();
        for (int o = 1; o < 256; o <<= 1) {
            int t = (tid >= o) ? lsc[tid - o] : 0;
            __syncthreads();
            lsc[tid] += t;
            __syncthreads();
        }
        int excl = lsc[tid] - v;
        lcnt_g[tid * 196 + blk] = v;
        lofs_g[tid * 196 + blk] = excl;
        lcur[tid] = excl;
        __syncthreads();
        for (int e = e0 + tid; e < e1; e += 256) {
            int d = dst[e], s = src[e];
            int b = d >> 8;
            int r = atomicAdd(&lcur[b], 1);
            tmp2[blk * CHUNK + r] = ((unsigned int)s << 8) | (unsigned int)(d & 255);
        }
        return;
    }
    // ---- GEMM half: split-bf16 (hi*hi+hi*lo+lo*hi ~ fp32) ----
    int wave = tid >> 6;
    int lane = tid & 63;
    int strip = (blockIdx.x - 196) * 4 + wave;
    if (strip >= NSTRIP) return;
    int rb = strip << 4;
    int m = lane & 15;
    int quad = lane >> 4;
    const float* ar = X + (size_t)(rb + m) * DD;
    f32x4 acc[8];
#pragma unroll
    for (int t = 0; t < 8; ++t) acc[t] = (f32x4){0.f, 0.f, 0.f, 0.f};
#pragma unroll
    for (int kk = 0; kk < 4; ++kk) {
        float4 xa = *(const float4*)(ar + kk * 32 + quad * 8);
        float4 xb = *(const float4*)(ar + kk * 32 + quad * 8 + 4);
        float xs[8] = {xa.x, xa.y, xa.z, xa.w, xb.x, xb.y, xb.z, xb.w};
        bf8_t ah, al;
#pragma unroll
        for (int j = 0; j < 8; ++j) {
            unsigned short hh = f2bf(xs[j]);
            ah[j] = (short)hh;
            al[j] = (short)f2bf(xs[j] - bf2f(hh));
        }
#pragma unroll
        for (int t = 0; t < 8; ++t) {
            size_t bo = ((size_t)(t * 4 + kk) * 64 + lane) * 8;
            bf8_t bh = *(const bf8_t*)(wh + bo);
            bf8_t bl = *(const bf8_t*)(wl + bo);
            acc[t] = __builtin_amdgcn_mfma_f32_16x16x32_bf16(ah, bh, acc[t], 0, 0, 0);
            acc[t] = __builtin_amdgcn_mfma_f32_16x16x32_bf16(ah, bl, acc[t], 0, 0, 0);
            acc[t] = __builtin_amdgcn_mfma_f32_16x16x32_bf16(al, bh, acc[t], 0, 0, 0);
        }
    }
    // C/D layout (m89-verified): col = lane&15, row = quad*4 + reg
#pragma unroll
    for (int t = 0; t < 8; ++t) {
#pragma unroll
        for (int r = 0; r < 4; ++r)
            H1[(size_t)(rb + quad * 4 + r) * DD + t * 16 + m] = f2bf(acc[t][r]);
    }
}

// per-bucket gather (binary search over 196 block-runs) + LDS counting sort
// -> padded CSR, per-node (start,end), dinv.  Epilogue: g1 = bf16(dinv*h1)
// for this block's 256 nodes (coalesced 64KB R/W) so agg passes need NO
// per-edge dinv load.
__global__ __launch_bounds__(256) void k_sort(const int* __restrict__ lcnt_g,
                                              const int* __restrict__ lofs_g,
                                              const unsigned int* __restrict__ tmp2,
                                              ushort* __restrict__ csru,
                                              int2* __restrict__ offs2,
                                              float* __restrict__ dinv,
                                              const ushort* __restrict__ h1,
                                              ushort* __restrict__ g1) {
    __shared__ unsigned int ent[MAXB];
    __shared__ int c[256];
    __shared__ int p[256];
    __shared__ int o[256];
    __shared__ int cnt[256];
    __shared__ int boff[256];
    __shared__ int cur[256];
    __shared__ float sdinv[256];
    int b = blockIdx.x, tid = threadIdx.x;
    int cv = (tid < 196) ? lcnt_g[b * 196 + tid] : 0;
    o[tid] = (tid < 196) ? lofs_g[b * 196 + tid] : 0;
    c[tid] = cv;
    p[tid] = cv;
    cnt[tid] = 0;
    __syncthreads();
    for (int s = 1; s < 256; s <<= 1) {
        int t = (tid >= s) ? p[tid - s] : 0;
        __syncthreads();
        p[tid] += t;
        __syncthreads();
    }
    int nb = p[255];
    for (int i = tid; i < nb; i += 256) {
        int lo = 0, hi = 255;
#pragma unroll
        for (int it = 0; it < 8; ++it) {
            int mid = (lo + hi) >> 1;
            if (p[mid] > i) hi = mid; else lo = mid + 1;
        }
        int blk = lo;
        int j = i - (p[blk] - c[blk]);
        unsigned int e = tmp2[blk * CHUNK + o[blk] + j];
        ent[i] = e;
        atomicAdd(&cnt[e & 255], 1);
    }
    __syncthreads();
    int v = cnt[tid];
    boff[tid] = v;
    __syncthreads();
    for (int s = 1; s < 256; s <<= 1) {
        int t = (tid >= s) ? boff[tid - s] : 0;
        __syncthreads();
        boff[tid] += t;
        __syncthreads();
    }
    int excl = boff[tid] - v;
    int base = b * MAXB;
    int node = b * 256 + tid;
    float dv = rsqrtf((float)(v + 1));
    sdinv[tid] = dv;
    if (node < NN) {
        offs2[node] = make_int2(base + excl, base + excl + v);
        dinv[node] = dv;
    }
    cur[tid] = excl;
    __syncthreads();
    for (int i = tid; i < nb; i += 256) {
        unsigned int e = ent[i];
        int bin = e & 255;
        int r = atomicAdd(&cur[bin], 1);
        csru[base + r] = (ushort)(e >> 8);
    }
    // ---- epilogue: g1 rows for this block's nodes (16 ushort8 per row) ----
    int rmax = NN - b * 256;
    if (rmax > 256) rmax = 256;
    for (int ci = tid; ci < rmax * 16; ci += 256) {
        int row = ci >> 4;
        int c8 = ci & 15;
        float dd = sdinv[row];
        size_t idx = ((size_t)(b * 256 + row)) * DD + c8 * 8;
        us8 hv = *(const us8*)(h1 + idx);
        us8 gv;
#pragma unroll
        for (int j = 0; j < 8; ++j) gv[j] = f2bf(dd * bf2f(hv[j]));
        *(us8*)(g1 + idx) = gv;
    }
}

// aggregation over pre-scaled rows: s = sum_{e} g[src_e] + g[node];
// out = relu(dinv_node * s + bias).  One wave per node; 4 quarter-waves x
// ushort8; 4x unroll -> 16 independent row gathers in flight.
// OUTMODE 0: fp32 out.  OUTMODE 1: Dekker bf16 hi/lo pair (feeds mgemm2).
template <int OUTMODE>
__global__ void k_agg(const ushort* __restrict__ g, const float* __restrict__ dinv,
                      const int2* __restrict__ offs2, const ushort* __restrict__ csru,
                      const float* __restrict__ bias, float* __restrict__ outf,
                      ushort* __restrict__ oh, ushort* __restrict__ ol) {
    int wave = threadIdx.x >> 6;
    int lane = threadIdx.x & 63;
    int node = blockIdx.x * 4 + wave;   // grid = NN/4 exactly
    int q = lane >> 4;
    int l = lane & 15;
    float a0[8] = {0.f, 0.f, 0.f, 0.f, 0.f, 0.f, 0.f, 0.f};
    float a1[8] = {0.f, 0.f, 0.f, 0.f, 0.f, 0.f, 0.f, 0.f};
    float a2[8] = {0.f, 0.f, 0.f, 0.f, 0.f, 0.f, 0.f, 0.f};
    float a3[8] = {0.f, 0.f, 0.f, 0.f, 0.f, 0.f, 0.f, 0.f};
    int2 oe = offs2[node];
    int e  = oe.x + q;
    int e1 = oe.y;
    for (; e + 12 < e1; e += 16) {
        int s0 = csru[e];
        int s1 = csru[e + 4];
        int s2 = csru[e + 8];
        int s3 = csru[e + 12];
        us8 v0 = *(const us8*)(g + (size_t)s0 * DD + 8 * l);
        us8 v1 = *(const us8*)(g + (size_t)s1 * DD + 8 * l);
        us8 v2 = *(const us8*)(g + (size_t)s2 * DD + 8 * l);
        us8 v3 = *(const us8*)(g + (size_t)s3 * DD + 8 * l);
#pragma unroll
        for (int j = 0; j < 8; ++j) {
            a0[j] += bf2f(v0[j]);
            a1[j] += bf2f(v1[j]);
            a2[j] += bf2f(v2[j]);
            a3[j] += bf2f(v3[j]);
        }
    }
    for (; e < e1; e += 4) {
        int s0 = csru[e];
        us8 v0 = *(const us8*)(g + (size_t)s0 * DD + 8 * l);
#pragma unroll
        for (int j = 0; j < 8; ++j) a0[j] += bf2f(v0[j]);
    }
    if (q == 0) {  // self-loop: g[node] = dinv_n * h_n
        us8 v = *(const us8*)(g + (size_t)node * DD + 8 * l);
#pragma unroll
        for (int j = 0; j < 8; ++j) a0[j] += bf2f(v[j]);
    }
#pragma unroll
    for (int j = 0; j < 8; ++j) {
        a0[j] += a1[j] + a2[j] + a3[j];
        a0[j] += __shfl_xor(a0[j], 16, 64);
        a0[j] += __shfl_xor(a0[j], 32, 64);
    }
    if (q == 0) {
        float dnode = dinv[node];
        const float* bp = bias + 8 * l;
        float r[8];
#pragma unroll
        for (int j = 0; j < 8; ++j) r[j] = fmaxf(dnode * a0[j] + bp[j], 0.f);
        if (OUTMODE == 0) {
            float* op = outf + (size_t)node * DD + 8 * l;
            float4 o0 = {r[0], r[1], r[2], r[3]};
            float4 o1 = {r[4], r[5], r[6], r[7]};
            *(float4*)op = o0;
            *(float4*)(op + 4) = o1;
        } else {
            us8 hh, ll;
#pragma unroll
            for (int j = 0; j < 8; ++j) {
                unsigned short h = f2bf(r[j]);
                hh[j] = h;
                ll[j] = f2bf(r[j] - bf2f(h));
            }
            *(us8*)(oh + (size_t)node * DD + 8 * l) = hh;
            *(us8*)(ol + (size_t)node * DD + 8 * l) = ll;
        }
    }
}

// layer-2 MFMA GEMM from pre-split bf16 pairs (no in-register Dekker work).
// Epilogue scales by dinv -> g2.
__global__ __launch_bounds__(256) void k_mgemm2(const ushort* __restrict__ xh,
                                                const ushort* __restrict__ xl,
                                                const ushort* __restrict__ wh,
                                                const ushort* __restrict__ wl,
                                                const float* __restrict__ dinv,
                                                ushort* __restrict__ G) {
    int wave = threadIdx.x >> 6;
    int lane = threadIdx.x & 63;
    int strip = blockIdx.x * 4 + wave;
    if (strip >= NSTRIP) return;
    int rb = strip << 4;
    int m = lane & 15;
    int quad = lane >> 4;
    const ushort* arh = xh + (size_t)(rb + m) * DD;
    const ushort* arl = xl + (size_t)(rb + m) * DD;
    f32x4 acc[8];
#pragma unroll
    for (int t = 0; t < 8; ++t) acc[t] = (f32x4){0.f, 0.f, 0.f, 0.f};
#pragma unroll
    for (int kk = 0; kk < 4; ++kk) {
        bf8_t ah = *(const bf8_t*)(arh + kk * 32 + quad * 8);
        bf8_t al = *(const bf8_t*)(arl + kk * 32 + quad * 8);
#pragma unroll
        for (int t = 0; t < 8; ++t) {
            size_t bo = ((size_t)(t * 4 + kk) * 64 + lane) * 8;
            bf8_t bh = *(const bf8_t*)(wh + bo);
            bf8_t bl = *(const bf8_t*)(wl + bo);
            acc[t] = __builtin_amdgcn_mfma_f32_16x16x32_bf16(ah, bh, acc[t], 0, 0, 0);
            acc[t] = __builtin_amdgcn_mfma_f32_16x16x32_bf16(ah, bl, acc[t], 0, 0, 0);
            acc[t] = __builtin_amdgcn_mfma_f32_16x16x32_bf16(al, bh, acc[t], 0, 0, 0);
        }
    }
    float dv[4];
#pragma unroll
    for (int r = 0; r < 4; ++r) dv[r] = dinv[rb + quad * 4 + r];
#pragma unroll
    for (int t = 0; t < 8; ++t) {
#pragma unroll
        for (int r = 0; r < 4; ++r)
            G[(size_t)(rb + quad * 4 + r) * DD + t * 16 + m] = f2bf(dv[r] * acc[t][r]);
    }
}

extern "C" void kernel_launch(void* const* d_in, const int* in_sizes, int n_in,
                              void* d_out, int out_size, void* d_ws, size_t ws_size,
                              hipStream_t stream) {
    const float* x  = (const float*)d_in[0];
    const int*   ei = (const int*)d_in[1];
    const float* W1 = (const float*)d_in[2];
    const float* b1 = (const float*)d_in[3];
    const float* W2 = (const float*)d_in[4];
    const float* b2 = (const float*)d_in[5];
    float* out = (float*)d_out;

    const int* src = ei;        // edge_index[0]
    const int* dst = ei + NE;   // edge_index[1]

    int*          wsi  = (int*)d_ws;
    float*        wsf  = (float*)d_ws;
    ushort*       wsu  = (ushort*)d_ws;
    unsigned int* wsuw = (unsigned int*)d_ws;
    int*    lcnt_g = wsi + OF_LCNT;
    int*    lofs_g = wsi + OF_LOFS;
    float*  dinv   = wsf + OF_DINV;
    int2*   offs2  = (int2*)(wsi + OF_OFFS2);
    unsigned int* tmp2 = wsuw + OF_TMP2;
    ushort* csru   = wsu + (size_t)OF_CSRU * 2;
    ushort* h1     = wsu + (size_t)OF_H1 * 2;
    ushort* g1     = wsu + (size_t)OF_G1 * 2;
    ushort* xh     = wsu + (size_t)OF_XH * 2;
    ushort* xl     = wsu + (size_t)OF_XL * 2;
    ushort* g2     = wsu + (size_t)OF_G2 * 2;
    ushort* w1h    = wsu + (size_t)OF_W1H * 2;
    ushort* w1l    = wsu + (size_t)OF_W1L * 2;
    ushort* w2h    = wsu + (size_t)OF_W2H * 2;
    ushort* w2l    = wsu + (size_t)OF_W2L * 2;

    // 1: W split tables
    hipLaunchKernelGGL(k_wconv, dim3(16), dim3(256), 0, stream,
                       W1, W2, w1h, w1l, w2h, w2l);
    // 2: edge shuffle (196 blocks) || layer-1 GEMM (782 blocks) -> h1
    hipLaunchKernelGGL(k_prep, dim3(196 + (NSTRIP + 3) / 4), dim3(256), 0, stream,
                       src, dst, lcnt_g, lofs_g, tmp2, x, w1h, w1l, h1);
    // 3: sort -> CSR + offs2 + dinv ; epilogue g1 = dinv*h1
    hipLaunchKernelGGL(k_sort, dim3(NB), dim3(256), 0, stream,
                       lcnt_g, lofs_g, tmp2, csru, offs2, dinv, h1, g1);
    // 4: agg layer 1 -> x2 as bf16 hi/lo
    hipLaunchKernelGGL(k_agg<1>, dim3(NN / 4), dim3(256), 0, stream,
                       g1, dinv, offs2, csru, b1, (float*)nullptr, xh, xl);
    // 5: layer-2 GEMM -> g2 = dinv*(x2@W2)
    hipLaunchKernelGGL(k_mgemm2, dim3((NSTRIP + 3) / 4), dim3(256), 0, stream,
                       xh, xl, w2h, w2l, dinv, g2);
    // 6: agg layer 2 -> out
    hipLaunchKernelGGL(k_agg<0>, dim3(NN / 4), dim3(256), 0, stream,
                       g2, dinv, offs2, csru, b2, out, (ushort*)nullptr, (ushort*)nullptr);
}